// Round 2
// baseline (247.174 us; speedup 1.0000x reference)
//
#include <hip/hip_runtime.h>
#include <math.h>

#define VOCAB 1024
#define ED 64
#define NROWS 65536            // 64*32*32 flattened rows
#define NELEM 4194304          // 64*64*32*32
#define CHUNK 128              // codes staged to LDS per iteration

// ws layout:
//   [0,    4096) : float  e2f[1024]   (fl32 of fp64 ||e_v||^2)
//   [4096, 4104) : double loss_sum
//   [4104, 8200) : unsigned hist[1024]

__global__ void vq_e2_kernel(const float* __restrict__ emb,
                             float* __restrict__ e2f) {
    int v = blockIdx.x * blockDim.x + threadIdx.x;
    if (v < VOCAB) {
        double s = 0.0;
        #pragma unroll
        for (int d = 0; d < ED; ++d) {
            double x = (double)emb[v * ED + d];
            s = fma(x, x, s);
        }
        e2f[v] = (float)s;
    }
}

__global__ __launch_bounds__(256, 2)
void vq_main_kernel(const float* __restrict__ z,
                    const float* __restrict__ emb,
                    const float* __restrict__ e2f,
                    float* __restrict__ out,
                    double* __restrict__ loss_sum,
                    unsigned* __restrict__ hist) {
    // 32 KB: one chunk of the codebook (fp32), reused as merge scratch at end
    __shared__ float lds[CHUNK * ED];

    const int t = threadIdx.x;
    const int q = t >> 6;          // code-quarter (== wave id)
    const int r = t & 63;          // lane
    const int bk = blockIdx.x;     // 512 blocks; 128 rows per block
    const int n0 = bk * 128 + r;   // this thread's row 0 (row 1 = n0 + 64)
    const int b  = bk >> 3;        // batch index
    const int s0 = n0 & 1023;      // spatial index h*32+w

    // flat_z[n][d] = z[b*65536 + d*1024 + s]
    const float* zp0 = z + b * 65536 + s0;
    const float* zp1 = zp0 + 64;

    float z0[ED], z1[ED];
    #pragma unroll
    for (int d = 0; d < ED; ++d) { z0[d] = zp0[d * 1024]; z1[d] = zp1[d * 1024]; }

    // A = ||z||^2: fp64 -> fl32. Per-row constant: any k-ulp offset vs numpy's
    // pairwise fp32 sum propagates exactly through the two subsequent fp32
    // roundings (same exponent grid) -> argmin invariant.
    double a0 = 0.0, a1 = 0.0;
    #pragma unroll
    for (int d = 0; d < ED; ++d) {
        a0 = fma((double)z0[d], (double)z0[d], a0);
        a1 = fma((double)z1[d], (double)z1[d], a1);
    }
    const float zn0 = (float)a0, zn1 = (float)a1;

    float best0 = 3.4e38f, best1 = 3.4e38f;
    int idx0 = 0, idx1 = 0;

    const float4* emb4 = (const float4*)emb;
    for (int v0 = 0; v0 < VOCAB; v0 += CHUNK) {
        __syncthreads();
        float4* l4 = (float4*)lds;
        #pragma unroll
        for (int j = 0; j < (CHUNK * ED / 4) / 256; ++j) {  // 8 float4 / thread
            int i4 = j * 256 + t;
            l4[i4] = emb4[v0 * (ED / 4) + i4];
        }
        __syncthreads();

        // This wave's 32 codes of the chunk; all lanes read the same LDS
        // address -> broadcast, conflict-free.
        const float* eq = lds + (q * 32) * ED;
        #pragma unroll 1
        for (int cb = 0; cb < 32; cb += 4) {
            const float* c0 = eq + (cb + 0) * ED;
            const float* c1 = eq + (cb + 1) * ED;
            const float* c2 = eq + (cb + 2) * ED;
            const float* c3 = eq + (cb + 3) * ED;
            // 8 independent fp32 chains (4 codes x 2 rows); each chain is
            // STRICTLY sequential over k (replicates BLAS k-order FMA).
            float m00 = 0.f, m01 = 0.f, m10 = 0.f, m11 = 0.f;
            float m20 = 0.f, m21 = 0.f, m30 = 0.f, m31 = 0.f;
            #pragma unroll
            for (int k = 0; k < ED; k += 4) {
                float4 e0 = *(const float4*)(c0 + k);
                float4 e1 = *(const float4*)(c1 + k);
                float4 e2v = *(const float4*)(c2 + k);
                float4 e3 = *(const float4*)(c3 + k);
                m00 = fmaf(z0[k+0], e0.x, m00);  m00 = fmaf(z0[k+1], e0.y, m00);
                m00 = fmaf(z0[k+2], e0.z, m00);  m00 = fmaf(z0[k+3], e0.w, m00);
                m01 = fmaf(z1[k+0], e0.x, m01);  m01 = fmaf(z1[k+1], e0.y, m01);
                m01 = fmaf(z1[k+2], e0.z, m01);  m01 = fmaf(z1[k+3], e0.w, m01);
                m10 = fmaf(z0[k+0], e1.x, m10);  m10 = fmaf(z0[k+1], e1.y, m10);
                m10 = fmaf(z0[k+2], e1.z, m10);  m10 = fmaf(z0[k+3], e1.w, m10);
                m11 = fmaf(z1[k+0], e1.x, m11);  m11 = fmaf(z1[k+1], e1.y, m11);
                m11 = fmaf(z1[k+2], e1.z, m11);  m11 = fmaf(z1[k+3], e1.w, m11);
                m20 = fmaf(z0[k+0], e2v.x, m20); m20 = fmaf(z0[k+1], e2v.y, m20);
                m20 = fmaf(z0[k+2], e2v.z, m20); m20 = fmaf(z0[k+3], e2v.w, m20);
                m21 = fmaf(z1[k+0], e2v.x, m21); m21 = fmaf(z1[k+1], e2v.y, m21);
                m21 = fmaf(z1[k+2], e2v.z, m21); m21 = fmaf(z1[k+3], e2v.w, m21);
                m30 = fmaf(z0[k+0], e3.x, m30);  m30 = fmaf(z0[k+1], e3.y, m30);
                m30 = fmaf(z0[k+2], e3.z, m30);  m30 = fmaf(z0[k+3], e3.w, m30);
                m31 = fmaf(z1[k+0], e3.x, m31);  m31 = fmaf(z1[k+1], e3.y, m31);
                m31 = fmaf(z1[k+2], e3.z, m31);  m31 = fmaf(z1[k+3], e3.w, m31);
            }
            // d = fl32( fl32(A + B_v) - 2*m )   (2*m exact in fp32)
            const int vb = v0 + q * 32 + cb;
            float tt, dd;
            tt = zn0 + e2f[vb+0]; dd = tt - 2.0f*m00; if (dd < best0) { best0 = dd; idx0 = vb+0; }
            tt = zn1 + e2f[vb+0]; dd = tt - 2.0f*m01; if (dd < best1) { best1 = dd; idx1 = vb+0; }
            tt = zn0 + e2f[vb+1]; dd = tt - 2.0f*m10; if (dd < best0) { best0 = dd; idx0 = vb+1; }
            tt = zn1 + e2f[vb+1]; dd = tt - 2.0f*m11; if (dd < best1) { best1 = dd; idx1 = vb+1; }
            tt = zn0 + e2f[vb+2]; dd = tt - 2.0f*m20; if (dd < best0) { best0 = dd; idx0 = vb+2; }
            tt = zn1 + e2f[vb+2]; dd = tt - 2.0f*m21; if (dd < best1) { best1 = dd; idx1 = vb+2; }
            tt = zn0 + e2f[vb+3]; dd = tt - 2.0f*m30; if (dd < best0) { best0 = dd; idx0 = vb+3; }
            tt = zn1 + e2f[vb+3]; dd = tt - 2.0f*m31; if (dd < best1) { best1 = dd; idx1 = vb+3; }
        }
    }

    // ---- merge the 4 code-quarters per row (tie -> smaller index, matching
    // np.argmin first-occurrence) ----
    __syncthreads();
    float* mb = lds;                 // [2][4][64]
    int*   mi = (int*)(lds + 512);   // [2][4][64]
    mb[q * 64 + r]       = best0;  mb[256 + q * 64 + r] = best1;
    mi[q * 64 + r]       = idx0;   mi[256 + q * 64 + r] = idx1;
    __syncthreads();

    if (q == 0) {
        float bv0 = mb[r];       int bi0 = mi[r];
        float bv1 = mb[256 + r]; int bi1 = mi[256 + r];
        #pragma unroll
        for (int qq = 1; qq < 4; ++qq) {
            float dv0 = mb[qq * 64 + r];       int iv0 = mi[qq * 64 + r];
            float dv1 = mb[256 + qq * 64 + r]; int iv1 = mi[256 + qq * 64 + r];
            if (dv0 < bv0 || (dv0 == bv0 && iv0 < bi0)) { bv0 = dv0; bi0 = iv0; }
            if (dv1 < bv1 || (dv1 == bv1 && iv1 < bi1)) { bv1 = dv1; bi1 = iv1; }
        }

        double lsum = 0.0;

        // ---- row 0 epilogue ----
        out[NELEM + n0] = (float)bi0;
        atomicAdd(&hist[bi0], 1u);
        {
            const float4* eb4 = (const float4*)(emb + bi0 * ED);
            float* outz = out + b * 65536 + s0;
            #pragma unroll
            for (int g = 0; g < 16; ++g) {
                float4 ev = eb4[g];
                float e4[4] = {ev.x, ev.y, ev.z, ev.w};
                #pragma unroll
                for (int c = 0; c < 4; ++c) {
                    int d = g * 4 + c;
                    float zef = z0[d];
                    outz[d * 1024] = zef + (e4[c] - zef);
                    double df = (double)e4[c] - (double)z0[d];
                    lsum = fma(df, df, lsum);
                }
            }
        }
        // ---- row 1 epilogue ----
        out[NELEM + n0 + 64] = (float)bi1;
        atomicAdd(&hist[bi1], 1u);
        {
            const float4* eb4 = (const float4*)(emb + bi1 * ED);
            float* outz = out + b * 65536 + s0 + 64;
            #pragma unroll
            for (int g = 0; g < 16; ++g) {
                float4 ev = eb4[g];
                float e4[4] = {ev.x, ev.y, ev.z, ev.w};
                #pragma unroll
                for (int c = 0; c < 4; ++c) {
                    int d = g * 4 + c;
                    float zef = z1[d];
                    outz[d * 1024] = zef + (e4[c] - zef);
                    double df = (double)e4[c] - (double)z1[d];
                    lsum = fma(df, df, lsum);
                }
            }
        }

        // wave reduce + one fp64 atomic per block
        #pragma unroll
        for (int off = 32; off > 0; off >>= 1)
            lsum += __shfl_down(lsum, off, 64);
        if (r == 0) atomicAdd(loss_sum, lsum);
    }
}

__global__ void vq_finalize_kernel(const unsigned* __restrict__ hist,
                                   const double* __restrict__ loss_sum,
                                   float* __restrict__ out) {
    __shared__ double red[256];
    int t = threadIdx.x;
    double ssum = 0.0;
    for (int i = t; i < VOCAB; i += 256) {
        double p = (double)hist[i] / (double)NROWS;
        ssum += p * log(p + 1e-10);
    }
    red[t] = ssum;
    __syncthreads();
    for (int off = 128; off > 0; off >>= 1) {
        if (t < off) red[t] += red[t + off];
        __syncthreads();
    }
    if (t == 0) {
        double qv = loss_sum[0] / (double)NELEM;
        out[NELEM + NROWS + 0] = (float)qv;            // quantization_loss
        out[NELEM + NROWS + 1] = (float)(qv * 0.25);   // commitment_loss
        out[NELEM + NROWS + 2] = (float)exp(-red[0]);  // perplexity
    }
}

extern "C" void kernel_launch(void* const* d_in, const int* in_sizes, int n_in,
                              void* d_out, int out_size, void* d_ws, size_t ws_size,
                              hipStream_t stream) {
    const float* z   = (const float*)d_in[0];   // (64,64,32,32) fp32
    const float* emb = (const float*)d_in[1];   // (1024,64) fp32
    float* out = (float*)d_out;

    float*    e2f      = (float*)d_ws;
    double*   loss_sum = (double*)((char*)d_ws + 4096);
    unsigned* hist     = (unsigned*)((char*)d_ws + 4104);

    hipMemsetAsync(d_ws, 0, 8200, stream);

    vq_e2_kernel<<<dim3(VOCAB / 256), dim3(256), 0, stream>>>(emb, e2f);
    vq_main_kernel<<<dim3(NROWS / 128), dim3(256), 0, stream>>>(
        z, emb, e2f, out, loss_sum, hist);
    vq_finalize_kernel<<<dim3(1), dim3(256), 0, stream>>>(hist, loss_sum, out);
}